// Round 1
// baseline (216.580 us; speedup 1.0000x reference)
//
#include <hip/hip_runtime.h>

// Multi-head causal attention fwd, B=2 S=2048 D=1024 H=16 DK=DV=64.
// fp32 I/O; internal bf16 MFMA pipeline.
// 4 dispatches: convert, fused-QKV gemm, flash-attn, final gemm.
// v7: attn rewritten LDS-free in the main loop. Waves split the 128-key tile
// (32 keys each); S^T = K Q^T with permuted key rows so P^T B-frags are
// built lane-locally (no sP round-trip, no shuffles, no in-loop barriers).
// K/V/Q load global->register directly; per-wave partial O^T/l reduced via
// LDS once per block (stride-65 padding, conflict-free).

typedef __bf16 bf16;
typedef __bf16 bf16x4 __attribute__((ext_vector_type(4)));
typedef __bf16 bf16x8 __attribute__((ext_vector_type(8)));
typedef float  f32x4  __attribute__((ext_vector_type(4)));

#define B_  2
#define S_  2048
#define D_  1024
#define H_  16
#define HD  64
#define NEG_BIG (-3.0e38f)
#define SCALE_LOG2E 0.1803368801111204f   // (1/8) * log2(e)

__device__ __forceinline__ void lds16(const void* g, void* l) {
    __builtin_amdgcn_global_load_lds((const __attribute__((address_space(1))) void*)g,
                                     (__attribute__((address_space(3))) void*)l, 16, 0, 0);
}

__device__ __forceinline__ f32x4 mfma16(bf16x8 a, bf16x8 b, f32x4 c) {
    return __builtin_amdgcn_mfma_f32_16x16x32_bf16(a, b, c, 0, 0, 0);
}

// ---------------- fp32 -> bf16 convert pre-pass ----------------
__global__ __launch_bounds__(256) void convert_k(const float* __restrict__ X,
                                                 const float* __restrict__ wq,
                                                 const float* __restrict__ wk,
                                                 const float* __restrict__ wv,
                                                 const float* __restrict__ wo,
                                                 bf16* __restrict__ dst) {
    const int gid = blockIdx.x * 256 + threadIdx.x;
    const int i   = gid * 4;
    const float* src;
    int off;
    if      (i < (4 << 20)) { src = X;  off = 0; }
    else if (i < (5 << 20)) { src = wq; off = 4 << 20; }
    else if (i < (6 << 20)) { src = wk; off = 5 << 20; }
    else if (i < (7 << 20)) { src = wv; off = 6 << 20; }
    else                    { src = wo; off = 7 << 20; }
    const float4 v = *(const float4*)(src + (i - off));
    bf16x4 p;
    p[0] = (bf16)v.x; p[1] = (bf16)v.y; p[2] = (bf16)v.z; p[3] = (bf16)v.w;
    *(bf16x4*)(dst + i) = p;
}

// ---------------- fused QKV GEMM (768 blocks = 3/CU) ----------------
// seg 0: Q = X Wq^T (+bq)*SCALE_LOG2E -> [B,H,S,64]
// seg 1: K = X Wk^T (+bk)             -> [B,H,S,64]
// seg 2: V = X Wv^T (+bv)             -> [B,H,64,S] (bf16x4 along s; L2 merges)
__global__ __launch_bounds__(256) void gemm_qkv(const bf16* __restrict__ A,
                                                const bf16* __restrict__ Wq,
                                                const bf16* __restrict__ Wk,
                                                const bf16* __restrict__ Wv,
                                                const float* __restrict__ bq,
                                                const float* __restrict__ bk,
                                                const float* __restrict__ bv,
                                                bf16* __restrict__ Qw,
                                                bf16* __restrict__ Kw,
                                                bf16* __restrict__ Vw) {
    constexpr int K = 1024;
    __shared__ bf16 sA[128 * 32];
    __shared__ bf16 sB[128 * 32];
    const int tid  = threadIdx.x;
    const int l15  = tid & 15;
    const int quad = (tid & 63) >> 4;
    const int wid  = tid >> 6;
    const int seg  = blockIdx.x >> 3;
    const int bn   = blockIdx.x & 7;
    const int bm   = blockIdx.y;
    const int wm   = (wid >> 1) * 64;
    const int wn   = (wid & 1) * 64;

    const bf16* W    = (seg == 0) ? Wq : (seg == 1) ? Wk : Wv;
    const float* bias = (seg == 0) ? bq : (seg == 1) ? bk : bv;

    const bf16* Ab = A + (size_t)bm * 128 * K;
    const bf16* Wb = W + (size_t)bn * 128 * K;

    f32x4 acc[4][4] = {};

    for (int k0 = 0; k0 < K; k0 += 32) {
        __syncthreads();
        #pragma unroll
        for (int it = 0; it < 2; ++it) {
            int c = it * 256 + tid;
            int row = c >> 2, c8 = c & 3;
            lds16(Ab + row * K + k0 + c8 * 8, (char*)sA + c * 16);
            lds16(Wb + row * K + k0 + c8 * 8, (char*)sB + c * 16);
        }
        __syncthreads();
        bf16x8 af[4], bfr[4];
        #pragma unroll
        for (int i = 0; i < 4; ++i)
            af[i] = *(const bf16x8*)&sA[(wm + i * 16 + l15) * 32 + quad * 8];
        #pragma unroll
        for (int i = 0; i < 4; ++i)
            bfr[i] = *(const bf16x8*)&sB[(wn + i * 16 + l15) * 32 + quad * 8];
        #pragma unroll
        for (int mi = 0; mi < 4; ++mi)
            #pragma unroll
            for (int ni = 0; ni < 4; ++ni)
                acc[mi][ni] = mfma16(af[mi], bfr[ni], acc[mi][ni]);
    }

    #pragma unroll
    for (int ni = 0; ni < 4; ++ni) {
        const int n  = bn * 128 + wn + ni * 16 + l15;
        const float bv_ = bias[n];
        const int h = n >> 6;
        #pragma unroll
        for (int mi = 0; mi < 4; ++mi) {
            const int m0 = bm * 128 + wm + mi * 16 + quad * 4;
            if (seg == 2) {   // V transposed: [B,H,64,S]
                const int dv = n & 63;
                const int b = m0 >> 11, s = m0 & 2047;
                bf16x4 pack;
                #pragma unroll
                for (int r = 0; r < 4; ++r) pack[r] = (bf16)(acc[mi][ni][r] + bv_);
                *(bf16x4*)&Vw[(((size_t)(b * H_ + h) * HD + dv) << 11) + s] = pack;
            } else {          // Q,K: [B,H,S,64]
                bf16* C = (seg == 0) ? Qw : Kw;
                const float qs = (seg == 0) ? SCALE_LOG2E : 1.0f;
                const int dk = n & 63;
                #pragma unroll
                for (int r = 0; r < 4; ++r) {
                    const int m = m0 + r, b = m >> 11, s = m & 2047;
                    C[(((size_t)(b * H_ + h) << 11) + s) * HD + dk] =
                        (bf16)((acc[mi][ni][r] + bv_) * qs);
                }
            }
        }
    }
}

// ---------------- final GEMM: out fp32 = A @ Wo^T + bias (512 blocks) -------
__global__ __launch_bounds__(256) void gemm_fin(const bf16* __restrict__ A,
                                                const bf16* __restrict__ W,
                                                const float* __restrict__ bias,
                                                float* __restrict__ C) {
    constexpr int N = 1024, K = 1024;
    __shared__ bf16 sA[64 * 32];
    __shared__ bf16 sB[128 * 32];
    const int tid  = threadIdx.x;
    const int l15  = tid & 15;
    const int quad = (tid & 63) >> 4;
    const int wid  = tid >> 6;
    const int bm   = blockIdx.x >> 3;
    const int bn   = blockIdx.x & 7;
    const int wm   = (wid & 1) * 32;
    const int wn   = (wid >> 1) * 64;

    const bf16* Ab = A + (size_t)bm * 64 * K;
    const bf16* Wb = W + (size_t)bn * 128 * K;

    f32x4 acc[2][4] = {};

    for (int k0 = 0; k0 < K; k0 += 32) {
        __syncthreads();
        {
            int c = tid, row = c >> 2, c8 = c & 3;
            lds16(Ab + row * K + k0 + c8 * 8, (char*)sA + c * 16);
        }
        #pragma unroll
        for (int it = 0; it < 2; ++it) {
            int c = it * 256 + tid;
            int row = c >> 2, c8 = c & 3;
            lds16(Wb + row * K + k0 + c8 * 8, (char*)sB + c * 16);
        }
        __syncthreads();
        bf16x8 af[2], bfr[4];
        #pragma unroll
        for (int i = 0; i < 2; ++i)
            af[i] = *(const bf16x8*)&sA[(wm + i * 16 + l15) * 32 + quad * 8];
        #pragma unroll
        for (int i = 0; i < 4; ++i)
            bfr[i] = *(const bf16x8*)&sB[(wn + i * 16 + l15) * 32 + quad * 8];
        #pragma unroll
        for (int mi = 0; mi < 2; ++mi)
            #pragma unroll
            for (int ni = 0; ni < 4; ++ni)
                acc[mi][ni] = mfma16(af[mi], bfr[ni], acc[mi][ni]);
    }

    #pragma unroll
    for (int ni = 0; ni < 4; ++ni) {
        const int n  = bn * 128 + wn + ni * 16 + l15;
        const float bv = bias[n];
        #pragma unroll
        for (int mi = 0; mi < 2; ++mi) {
            const int m0 = bm * 64 + wm + mi * 16 + quad * 4;
            #pragma unroll
            for (int r = 0; r < 4; ++r)
                C[(size_t)(m0 + r) * N + n] = acc[mi][ni][r] + bv;
        }
    }
}

// ---------------- Flash attention v7 — LDS-free main loop ----------------
// 256 threads (4 waves), 64-q tile, 128-key tiles; each wave owns 32 keys of
// every tile and accumulates a partial O^T (64dv x 64q over its keys).
// S^T = K Q^T with permuted K rows: C layout (q=l15, key=quad*8+f*4+r) IS the
// PV B-frag layout -> P^T built by lane-local bf16 packing. Fixed-shift
// softmax (Q pre-scaled); l = ones*P^T rides the MFMA pipe. K double-buffered
// in registers. One LDS reduction per block at the end (stride-65 pad).
__global__ __launch_bounds__(256, 2) void attn_k(const bf16* __restrict__ Q,
                                                 const bf16* __restrict__ K,
                                                 const bf16* __restrict__ Vt,
                                                 const float* __restrict__ pmask,
                                                 bf16* __restrict__ Aout) {
    __shared__ float sO[4 * 64 * 65];   // per-wave O^T partials, padded
    __shared__ float sL[4 * 64];        // per-wave l partials
    const int tid  = threadIdx.x;
    const int l15  = tid & 15;
    const int quad = (tid & 63) >> 4;
    const int wid  = tid >> 6;           // 0..3 -> key quarter
    const int j    = blockIdx.x >> 5;    // 0..31
    const int bh   = blockIdx.x & 31;
    const int b    = bh >> 4;
    const int h    = bh & 15;
    // stride-256 balance: a CU's 4 blocks have j = {t, t+8, t+16, t+24}
    const int a_  = j >> 3, bq_ = j & 7;
    const int qt  = (a_ == 0) ? (31 - bq_) : (a_ == 1) ? bq_
                  : (a_ == 2) ? (23 - bq_) : (8 + bq_);
    const int nkt = (qt >> 1) + 1;       // # 128-key tiles (causal)

    const bf16* Qg = Q  + ((size_t)bh * S_ + qt * 64) * HD;
    const bf16* Kg = K  + (size_t)bh * S_ * HD;
    const bf16* Vg = Vt + (size_t)bh * HD * S_;

    // Q B-frags live in registers for the whole block: n=q=l15, k=kk*32+quad*8+j
    bf16x8 qb[4][2];
    #pragma unroll
    for (int qf = 0; qf < 4; ++qf)
        #pragma unroll
        for (int kk = 0; kk < 2; ++kk)
            qb[qf][kk] = *(const bf16x8*)&Qg[(qf * 16 + l15) * HD + kk * 32 + quad * 8];

    // permuted key row for K A-frags: lane l15 of frag f holds key
    // (l15>>2)*8 + f*4 + (l15&3)  => C row (quad*4+r) <-> key quad*8+f*4+r
    const int krow0 = (l15 >> 2) * 8 + (l15 & 3);
    const int wkey  = wid * 32;          // wave's key base within 128-tile

    bf16x8 onesv;
    #pragma unroll
    for (int i = 0; i < 8; ++i) onesv[i] = (bf16)1.0f;

    f32x4 o[4][4] = {};                  // O^T partial: [dvf][qf]
    f32x4 lacc[4] = {};                  // l partial:   [qf] (rows replicated)

    // K double buffer in registers
    bf16x8 kaA[2][2], kaB[2][2];         // [f][kk]
    #pragma unroll
    for (int f = 0; f < 2; ++f)
        #pragma unroll
        for (int kk = 0; kk < 2; ++kk)
            kaA[f][kk] = *(const bf16x8*)
                &Kg[(size_t)(wkey + krow0 + f * 4) * HD + kk * 32 + quad * 8];

#define TILE(KC, KN, KT)                                                        \
  {                                                                             \
    const int kb = (KT) * 128 + wkey;                                           \
    const bool lastt = ((KT) == nkt - 1);                                       \
    bf16x8 va[4];                                                               \
    _Pragma("unroll")                                                           \
    for (int dvf = 0; dvf < 4; ++dvf)                                           \
        va[dvf] = *(const bf16x8*)                                              \
            &Vg[(size_t)(dvf * 16 + l15) * S_ + kb + quad * 8];                 \
    f32x4 s[2][4] = {};                                                         \
    _Pragma("unroll")                                                           \
    for (int f = 0; f < 2; ++f)                                                 \
        _Pragma("unroll")                                                       \
        for (int qf = 0; qf < 4; ++qf) {                                        \
            s[f][qf] = mfma16(KC[f][0], qb[qf][0], s[f][qf]);                   \
            s[f][qf] = mfma16(KC[f][1], qb[qf][1], s[f][qf]);                   \
        }                                                                       \
    if ((KT) + 1 < nkt) {                                                       \
        const int kb2 = ((KT) + 1) * 128 + wkey;                                \
        _Pragma("unroll")                                                       \
        for (int f = 0; f < 2; ++f)                                             \
            _Pragma("unroll")                                                   \
            for (int kk = 0; kk < 2; ++kk)                                      \
                KN[f][kk] = *(const bf16x8*)                                    \
                    &Kg[(size_t)(kb2 + krow0 + f * 4) * HD + kk * 32 + quad * 8]; \
    }                                                                           \
    float pmadd[8];                                                             \
    _Pragma("unroll")                                                           \
    for (int f = 0; f < 2; ++f)                                                 \
        _Pragma("unroll")                                                       \
        for (int r = 0; r < 4; ++r)                                             \
            pmadd[f * 4 + r] =                                                  \
                (pmask[b * S_ + kb + quad * 8 + f * 4 + r] > 0.f) ? NEG_BIG : 0.f; \
    _Pragma("unroll")                                                           \
    for (int qf = 0; qf < 4; ++qf) {                                            \
        const int qg = qt * 64 + qf * 16 + l15;                                 \
        bf16x8 pb;                                                              \
        _Pragma("unroll")                                                       \
        for (int f = 0; f < 2; ++f)                                             \
            _Pragma("unroll")                                                   \
            for (int r = 0; r < 4; ++r) {                                       \
                float v = s[f][qf][r] + pmadd[f * 4 + r];                       \
                if (lastt && (kb + quad * 8 + f * 4 + r > qg)) v = NEG_BIG;     \
                pb[f * 4 + r] = (bf16)exp2f(v);                                 \
            }                                                                   \
        lacc[qf] = mfma16(onesv, pb, lacc[qf]);                                 \
        _Pragma("unroll")                                                       \
        for (int dvf = 0; dvf < 4; ++dvf)                                       \
            o[dvf][qf] = mfma16(va[dvf], pb, o[dvf][qf]);                       \
    }                                                                           \
  }

    int kt = 0;
    for (;;) {
        TILE(kaA, kaB, kt); if (++kt == nkt) break;
        TILE(kaB, kaA, kt); if (++kt == nkt) break;
    }
#undef TILE

    // ---- cross-wave reduction (once per block) ----
    {
        float* sOw = sO + wid * (64 * 65);
        #pragma unroll
        for (int dvf = 0; dvf < 4; ++dvf)
            #pragma unroll
            for (int qf = 0; qf < 4; ++qf)
                #pragma unroll
                for (int r = 0; r < 4; ++r)
                    sOw[(dvf * 16 + quad * 4 + r) * 65 + qf * 16 + l15] = o[dvf][qf][r];
        if (quad == 0) {
            #pragma unroll
            for (int qf = 0; qf < 4; ++qf)
                sL[wid * 64 + qf * 16 + l15] = lacc[qf][0];
        }
    }
    __syncthreads();
    {
        const int q   = tid >> 2;
        const int dvg = (tid & 3) * 16;
        const float l = sL[q] + sL[64 + q] + sL[128 + q] + sL[192 + q];
        const float inv = 1.f / l;
        bf16x8 p0, p1;
        #pragma unroll
        for (int i = 0; i < 8; ++i) {
            const int dv = dvg + i;
            float a = sO[dv * 65 + q] + sO[4160 + dv * 65 + q]
                    + sO[8320 + dv * 65 + q] + sO[12480 + dv * 65 + q];
            p0[i] = (bf16)(a * inv);
        }
        #pragma unroll
        for (int i = 0; i < 8; ++i) {
            const int dv = dvg + 8 + i;
            float a = sO[dv * 65 + q] + sO[4160 + dv * 65 + q]
                    + sO[8320 + dv * 65 + q] + sO[12480 + dv * 65 + q];
            p1[i] = (bf16)(a * inv);
        }
        const size_t base = ((size_t)b * S_ + qt * 64 + q) * D_ + h * HD + dvg;
        *(bf16x8*)&Aout[base]     = p0;
        *(bf16x8*)&Aout[base + 8] = p1;
    }
}

extern "C" void kernel_launch(void* const* d_in, const int* in_sizes, int n_in,
                              void* d_out, int out_size, void* d_ws, size_t ws_size,
                              hipStream_t stream) {
    const float* X   = (const float*)d_in[0];
    const float* pm  = (const float*)d_in[1];
    const float* wq  = (const float*)d_in[2];
    const float* bq  = (const float*)d_in[3];
    const float* wk  = (const float*)d_in[4];
    const float* bk  = (const float*)d_in[5];
    const float* wv  = (const float*)d_in[6];
    const float* bvb = (const float*)d_in[7];
    const float* wo  = (const float*)d_in[8];
    const float* bo  = (const float*)d_in[9];
    float* out = (float*)d_out;

    char* ws = (char*)d_ws;
    bf16* Xb  = (bf16*)(ws);                  // 4M elems  8 MiB
    bf16* Wqb = (bf16*)(ws + (8u  << 20));    // 1M elems  2 MiB each
    bf16* Wkb = (bf16*)(ws + (10u << 20));
    bf16* Wvb = (bf16*)(ws + (12u << 20));
    bf16* Wob = (bf16*)(ws + (14u << 20));
    bf16* Qw  = (bf16*)(ws + (16u << 20));    // [B,H,S,64]  8 MiB
    bf16* Kw  = (bf16*)(ws + (24u << 20));    // [B,H,S,64]  8 MiB
    bf16* Vw  = (bf16*)(ws + (32u << 20));    // [B,H,64,S]  8 MiB
    bf16* Aw  = (bf16*)(ws + (40u << 20));    // [B*S, 1024] 8 MiB

    convert_k<<<dim3(8192), dim3(256), 0, stream>>>(X, wq, wk, wv, wo, Xb);
    gemm_qkv<<<dim3(24, 32), dim3(256), 0, stream>>>(Xb, Wqb, Wkb, Wvb,
                                                     bq, bk, bvb, Qw, Kw, Vw);
    attn_k<<<dim3(1024), dim3(256), 0, stream>>>(Qw, Kw, Vw, pm, Aw);
    gemm_fin<<<dim3(512), dim3(256), 0, stream>>>(Aw, Wob, bo, out);
}

// Round 2
// 189.705 us; speedup vs baseline: 1.1417x; 1.1417x over previous
//
#include <hip/hip_runtime.h>

// Multi-head causal attention fwd, B=2 S=2048 D=1024 H=16 DK=DV=64.
// fp32 I/O; internal bf16 MFMA pipeline.
// 4 dispatches: convert, fused-QKV gemm, flash-attn, final gemm.
// v8: v6's memory architecture (LDS-staged K/V, 4 waves split 64 q-rows,
// 2 barriers/tile, 4+ blocks/CU) + v7's algebra (S^T = K Q^T with permuted
// K A-frag rows so the S^T output layout IS the PV B-frag layout).
// sP round-trip deleted (no swizzled scalar DS writes -> bank conflicts gone);
// l rides the MFMA pipe and stays lane-local; epilogue needs no LDS at all.
// Padding mask applied via one fmaf per element (pmask * NEG_BIG).

typedef __bf16 bf16;
typedef __bf16 bf16x4 __attribute__((ext_vector_type(4)));
typedef __bf16 bf16x8 __attribute__((ext_vector_type(8)));
typedef float  f32x4  __attribute__((ext_vector_type(4)));

#define B_  2
#define S_  2048
#define D_  1024
#define H_  16
#define HD  64
#define NEG_BIG (-3.0e38f)
#define SCALE_LOG2E 0.1803368801111204f   // (1/8) * log2(e)

__device__ __forceinline__ void lds16(const void* g, void* l) {
    __builtin_amdgcn_global_load_lds((const __attribute__((address_space(1))) void*)g,
                                     (__attribute__((address_space(3))) void*)l, 16, 0, 0);
}

__device__ __forceinline__ f32x4 mfma16(bf16x8 a, bf16x8 b, f32x4 c) {
    return __builtin_amdgcn_mfma_f32_16x16x32_bf16(a, b, c, 0, 0, 0);
}

// ---------------- fp32 -> bf16 convert pre-pass ----------------
__global__ __launch_bounds__(256) void convert_k(const float* __restrict__ X,
                                                 const float* __restrict__ wq,
                                                 const float* __restrict__ wk,
                                                 const float* __restrict__ wv,
                                                 const float* __restrict__ wo,
                                                 bf16* __restrict__ dst) {
    const int gid = blockIdx.x * 256 + threadIdx.x;
    const int i   = gid * 4;
    const float* src;
    int off;
    if      (i < (4 << 20)) { src = X;  off = 0; }
    else if (i < (5 << 20)) { src = wq; off = 4 << 20; }
    else if (i < (6 << 20)) { src = wk; off = 5 << 20; }
    else if (i < (7 << 20)) { src = wv; off = 6 << 20; }
    else                    { src = wo; off = 7 << 20; }
    const float4 v = *(const float4*)(src + (i - off));
    bf16x4 p;
    p[0] = (bf16)v.x; p[1] = (bf16)v.y; p[2] = (bf16)v.z; p[3] = (bf16)v.w;
    *(bf16x4*)(dst + i) = p;
}

// ---------------- fused QKV GEMM (768 blocks = 3/CU) ----------------
// seg 0: Q = X Wq^T (+bq)*SCALE_LOG2E -> [B,H,S,64]
// seg 1: K = X Wk^T (+bk)             -> [B,H,S,64]
// seg 2: V = X Wv^T (+bv)             -> [B,H,64,S] (bf16x4 along s; L2 merges)
__global__ __launch_bounds__(256) void gemm_qkv(const bf16* __restrict__ A,
                                                const bf16* __restrict__ Wq,
                                                const bf16* __restrict__ Wk,
                                                const bf16* __restrict__ Wv,
                                                const float* __restrict__ bq,
                                                const float* __restrict__ bk,
                                                const float* __restrict__ bv,
                                                bf16* __restrict__ Qw,
                                                bf16* __restrict__ Kw,
                                                bf16* __restrict__ Vw) {
    constexpr int K = 1024;
    __shared__ bf16 sA[128 * 32];
    __shared__ bf16 sB[128 * 32];
    const int tid  = threadIdx.x;
    const int l15  = tid & 15;
    const int quad = (tid & 63) >> 4;
    const int wid  = tid >> 6;
    const int seg  = blockIdx.x >> 3;
    const int bn   = blockIdx.x & 7;
    const int bm   = blockIdx.y;
    const int wm   = (wid >> 1) * 64;
    const int wn   = (wid & 1) * 64;

    const bf16* W    = (seg == 0) ? Wq : (seg == 1) ? Wk : Wv;
    const float* bias = (seg == 0) ? bq : (seg == 1) ? bk : bv;

    const bf16* Ab = A + (size_t)bm * 128 * K;
    const bf16* Wb = W + (size_t)bn * 128 * K;

    f32x4 acc[4][4] = {};

    for (int k0 = 0; k0 < K; k0 += 32) {
        __syncthreads();
        #pragma unroll
        for (int it = 0; it < 2; ++it) {
            int c = it * 256 + tid;
            int row = c >> 2, c8 = c & 3;
            lds16(Ab + row * K + k0 + c8 * 8, (char*)sA + c * 16);
            lds16(Wb + row * K + k0 + c8 * 8, (char*)sB + c * 16);
        }
        __syncthreads();
        bf16x8 af[4], bfr[4];
        #pragma unroll
        for (int i = 0; i < 4; ++i)
            af[i] = *(const bf16x8*)&sA[(wm + i * 16 + l15) * 32 + quad * 8];
        #pragma unroll
        for (int i = 0; i < 4; ++i)
            bfr[i] = *(const bf16x8*)&sB[(wn + i * 16 + l15) * 32 + quad * 8];
        #pragma unroll
        for (int mi = 0; mi < 4; ++mi)
            #pragma unroll
            for (int ni = 0; ni < 4; ++ni)
                acc[mi][ni] = mfma16(af[mi], bfr[ni], acc[mi][ni]);
    }

    #pragma unroll
    for (int ni = 0; ni < 4; ++ni) {
        const int n  = bn * 128 + wn + ni * 16 + l15;
        const float bv_ = bias[n];
        const int h = n >> 6;
        #pragma unroll
        for (int mi = 0; mi < 4; ++mi) {
            const int m0 = bm * 128 + wm + mi * 16 + quad * 4;
            if (seg == 2) {   // V transposed: [B,H,64,S]
                const int dv = n & 63;
                const int b = m0 >> 11, s = m0 & 2047;
                bf16x4 pack;
                #pragma unroll
                for (int r = 0; r < 4; ++r) pack[r] = (bf16)(acc[mi][ni][r] + bv_);
                *(bf16x4*)&Vw[(((size_t)(b * H_ + h) * HD + dv) << 11) + s] = pack;
            } else {          // Q,K: [B,H,S,64]
                bf16* C = (seg == 0) ? Qw : Kw;
                const float qs = (seg == 0) ? SCALE_LOG2E : 1.0f;
                const int dk = n & 63;
                #pragma unroll
                for (int r = 0; r < 4; ++r) {
                    const int m = m0 + r, b = m >> 11, s = m & 2047;
                    C[(((size_t)(b * H_ + h) << 11) + s) * HD + dk] =
                        (bf16)((acc[mi][ni][r] + bv_) * qs);
                }
            }
        }
    }
}

// ---------------- final GEMM: out fp32 = A @ Wo^T + bias (512 blocks) -------
__global__ __launch_bounds__(256) void gemm_fin(const bf16* __restrict__ A,
                                                const bf16* __restrict__ W,
                                                const float* __restrict__ bias,
                                                float* __restrict__ C) {
    constexpr int N = 1024, K = 1024;
    __shared__ bf16 sA[64 * 32];
    __shared__ bf16 sB[128 * 32];
    const int tid  = threadIdx.x;
    const int l15  = tid & 15;
    const int quad = (tid & 63) >> 4;
    const int wid  = tid >> 6;
    const int bm   = blockIdx.x >> 3;
    const int bn   = blockIdx.x & 7;
    const int wm   = (wid & 1) * 32;
    const int wn   = (wid >> 1) * 64;

    const bf16* Ab = A + (size_t)bm * 64 * K;
    const bf16* Wb = W + (size_t)bn * 128 * K;

    f32x4 acc[2][4] = {};

    for (int k0 = 0; k0 < K; k0 += 32) {
        __syncthreads();
        {
            int c = tid, row = c >> 2, c8 = c & 3;
            lds16(Ab + row * K + k0 + c8 * 8, (char*)sA + c * 16);
        }
        #pragma unroll
        for (int it = 0; it < 2; ++it) {
            int c = it * 256 + tid;
            int row = c >> 2, c8 = c & 3;
            lds16(Wb + row * K + k0 + c8 * 8, (char*)sB + c * 16);
        }
        __syncthreads();
        bf16x8 af[2], bfr[4];
        #pragma unroll
        for (int i = 0; i < 2; ++i)
            af[i] = *(const bf16x8*)&sA[(wm + i * 16 + l15) * 32 + quad * 8];
        #pragma unroll
        for (int i = 0; i < 4; ++i)
            bfr[i] = *(const bf16x8*)&sB[(wn + i * 16 + l15) * 32 + quad * 8];
        #pragma unroll
        for (int mi = 0; mi < 2; ++mi)
            #pragma unroll
            for (int ni = 0; ni < 4; ++ni)
                acc[mi][ni] = mfma16(af[mi], bfr[ni], acc[mi][ni]);
    }

    #pragma unroll
    for (int ni = 0; ni < 4; ++ni) {
        const int n  = bn * 128 + wn + ni * 16 + l15;
        const float bv = bias[n];
        #pragma unroll
        for (int mi = 0; mi < 2; ++mi) {
            const int m0 = bm * 64 + wm + mi * 16 + quad * 4;
            #pragma unroll
            for (int r = 0; r < 4; ++r)
                C[(size_t)(m0 + r) * N + n] = acc[mi][ni][r] + bv;
        }
    }
}

// ---------------- Flash attention v8 ----------------
// 256 threads (4 waves), 64-q tile, 128-key tiles, 32K LDS.
// Waves split q (16 rows each, q = lane&15 = MFMA n-index).
// S^T = K Q^T with permuted K A-frag rows: lane l15 of frag f holds key
// (l15>>2)*8 + f*4 + (l15&3), so C row quad*4+r <-> key quad*8+f*4+r, which
// is exactly the PV B-frag k-index (quad*8+j). P^T packs lane-locally.
// l = ones*P^T on the MFMA pipe, replicated per-lane -> LDS-free epilogue.
__global__ __launch_bounds__(256, 4) void attn_k(const bf16* __restrict__ Q,
                                                 const bf16* __restrict__ K,
                                                 const bf16* __restrict__ Vt,
                                                 const float* __restrict__ pmask,
                                                 bf16* __restrict__ Aout) {
    __shared__ bf16 sK_[2 * 128 * 32];   // 16K [kk][krow][32]
    __shared__ bf16 sV[4 * 64 * 32];     // 16K [kc][dv][32]   (V^T)
    const int tid  = threadIdx.x;
    const int l15  = tid & 15;
    const int quad = (tid & 63) >> 4;
    const int wid  = tid >> 6;           // 0..3 -> q quarter
    const int j    = blockIdx.x >> 5;    // 0..31
    const int bh   = blockIdx.x & 31;
    const int b    = bh >> 4;
    const int h    = bh & 15;
    // stride-256 balance: a CU's 4 blocks have j = {t, t+8, t+16, t+24}
    const int a_  = j >> 3, bq_ = j & 7;
    const int qt  = (a_ == 0) ? (31 - bq_) : (a_ == 1) ? bq_
                  : (a_ == 2) ? (23 - bq_) : (8 + bq_);
    const int nkt = (qt >> 1) + 1;       // # 128-key tiles (causal)

    const bf16* Qg = Q  + ((size_t)bh * S_ + qt * 64) * HD;
    const bf16* Kg = K  + (size_t)bh * S_ * HD;
    const bf16* Vg = Vt + (size_t)bh * HD * S_;

    // Q B-frags, direct from global (read once): n=q=l15, k=kk*32+quad*8+jj
    bf16x8 qb[2];
    #pragma unroll
    for (int kk = 0; kk < 2; ++kk)
        qb[kk] = *(const bf16x8*)&Qg[(wid * 16 + l15) * HD + kk * 32 + quad * 8];

    // permuted K row base: lane l15 of frag f reads key (l15>>2)*8 + f*4 + (l15&3)
    const int krow0 = (l15 >> 2) * 8 + (l15 & 3);
    const int qg    = qt * 64 + wid * 16 + l15;   // this lane's global q (col)

    bf16x8 onesv;
    #pragma unroll
    for (int i = 0; i < 8; ++i) onesv[i] = (bf16)1.0f;

    f32x4 o[4]  = {};                    // O^T: rows dv = dvf*16+quad*4+r, col q=l15
    f32x4 lacc  = {};                    // l[q], replicated across regs

    for (int kt = 0; kt < nkt; ++kt) {
        __syncthreads();                 // prev compute done with sK_/sV
        #pragma unroll
        for (int it = 0; it < 4; ++it) {
            int c = it * 256 + tid;
            { int pl = c >> 9, row = (c >> 2) & 127, c8 = c & 3;
              lds16(Kg + (size_t)kt * 128 * HD + row * HD + pl * 32 + c8 * 8,
                    (char*)sK_ + c * 16); }
            { int kc = c >> 8, dv = (c >> 2) & 63, c8 = c & 3;
              lds16(Vg + kt * 128 + dv * S_ + kc * 32 + c8 * 8,
                    (char*)sV + c * 16); }
        }
        // pmask prefetch for this tile (L1/L2-resident, independent of LDS)
        float4 pm4[8];
        #pragma unroll
        for (int g = 0; g < 4; ++g)
            #pragma unroll
            for (int f = 0; f < 2; ++f)
                pm4[g * 2 + f] = *(const float4*)
                    &pmask[b * S_ + kt * 128 + g * 32 + quad * 8 + f * 4];
        __syncthreads();                 // staging drained & visible

        const bool lastt = (kt == nkt - 1);
        #pragma unroll
        for (int g = 0; g < 4; ++g) {
            // S^T for 32-key group g: C rows = keys (permuted back), cols = q
            f32x4 s[2] = {};
            #pragma unroll
            for (int f = 0; f < 2; ++f)
                #pragma unroll
                for (int kk = 0; kk < 2; ++kk) {
                    bf16x8 ka = *(const bf16x8*)
                        &sK_[(kk * 128 + g * 32 + krow0 + f * 4) * 32 + quad * 8];
                    s[f] = mfma16(ka, qb[kk], s[f]);
                }
            // mask + exp2 -> P^T B-frag (lane-local pack)
            bf16x8 pb;
            #pragma unroll
            for (int f = 0; f < 2; ++f) {
                const float4 pmv = pm4[g * 2 + f];
                #pragma unroll
                for (int r = 0; r < 4; ++r) {
                    float v = fmaf(((const float*)&pmv)[r], NEG_BIG, s[f][r]);
                    if (lastt && (kt * 128 + g * 32 + quad * 8 + f * 4 + r > qg))
                        v = NEG_BIG;
                    pb[f * 4 + r] = (bf16)exp2f(v);
                }
            }
            lacc = mfma16(onesv, pb, lacc);          // l += sum_k P^T[k][q]
            #pragma unroll
            for (int dvf = 0; dvf < 4; ++dvf) {
                bf16x8 va = *(const bf16x8*)
                    &sV[(g * 64 + dvf * 16 + l15) * 32 + quad * 8];
                o[dvf] = mfma16(va, pb, o[dvf]);     // O^T += V^T P^T
            }
        }
    }

    // epilogue: fully lane-local. lane holds O[q][dv=dvf*16+quad*4+r], l[q].
    const float inv = 1.f / lacc[0];
    const size_t base = ((size_t)b * S_ + qg) * D_ + h * HD + quad * 4;
    #pragma unroll
    for (int dvf = 0; dvf < 4; ++dvf) {
        bf16x4 pack;
        #pragma unroll
        for (int r = 0; r < 4; ++r) pack[r] = (bf16)(o[dvf][r] * inv);
        *(bf16x4*)&Aout[base + dvf * 16] = pack;
    }
}

extern "C" void kernel_launch(void* const* d_in, const int* in_sizes, int n_in,
                              void* d_out, int out_size, void* d_ws, size_t ws_size,
                              hipStream_t stream) {
    const float* X   = (const float*)d_in[0];
    const float* pm  = (const float*)d_in[1];
    const float* wq  = (const float*)d_in[2];
    const float* bq  = (const float*)d_in[3];
    const float* wk  = (const float*)d_in[4];
    const float* bk  = (const float*)d_in[5];
    const float* wv  = (const float*)d_in[6];
    const float* bvb = (const float*)d_in[7];
    const float* wo  = (const float*)d_in[8];
    const float* bo  = (const float*)d_in[9];
    float* out = (float*)d_out;

    char* ws = (char*)d_ws;
    bf16* Xb  = (bf16*)(ws);                  // 4M elems  8 MiB
    bf16* Wqb = (bf16*)(ws + (8u  << 20));    // 1M elems  2 MiB each
    bf16* Wkb = (bf16*)(ws + (10u << 20));
    bf16* Wvb = (bf16*)(ws + (12u << 20));
    bf16* Wob = (bf16*)(ws + (14u << 20));
    bf16* Qw  = (bf16*)(ws + (16u << 20));    // [B,H,S,64]  8 MiB
    bf16* Kw  = (bf16*)(ws + (24u << 20));    // [B,H,S,64]  8 MiB
    bf16* Vw  = (bf16*)(ws + (32u << 20));    // [B,H,64,S]  8 MiB
    bf16* Aw  = (bf16*)(ws + (40u << 20));    // [B*S, 1024] 8 MiB

    convert_k<<<dim3(8192), dim3(256), 0, stream>>>(X, wq, wk, wv, wo, Xb);
    gemm_qkv<<<dim3(24, 32), dim3(256), 0, stream>>>(Xb, Wqb, Wkb, Wvb,
                                                     bq, bk, bvb, Qw, Kw, Vw);
    attn_k<<<dim3(1024), dim3(256), 0, stream>>>(Qw, Kw, Vw, pm, Aw);
    gemm_fin<<<dim3(512), dim3(256), 0, stream>>>(Aw, Wob, bo, out);
}